// Round 5
// baseline (58805.640 us; speedup 1.0000x reference)
//
#include <hip/hip_runtime.h>
#include <cstdint>
#include <cstddef>

#define T_LEN 4096
#define NSTEP (T_LEN + 2)

typedef _Float16 half8 __attribute__((ext_vector_type(8)));
typedef _Float16 half4 __attribute__((ext_vector_type(4)));
typedef float floatx4 __attribute__((ext_vector_type(4)));
typedef unsigned long long u64;

#define MFMA16(a, b, c) __builtin_amdgcn_mfma_f32_16x16x32_f16((a), (b), (c), 0, 0, 0)
#define SCOPE_AGENT __HIP_MEMORY_SCOPE_AGENT

// ---- workspace layout (bytes) ----
static constexpr size_t OFF_W1  = 0;                          // [2048][576] f16  (k<64: w_ih1, k>=64: w_hh1)
static constexpr size_t SZ_W1   = (size_t)2048 * 576 * 2;
static constexpr size_t OFF_W2  = OFF_W1 + SZ_W1;             // [2048][1024] f16 (k<512: w_ih2, k>=512: w_hh2)
static constexpr size_t SZ_W2   = (size_t)2048 * 1024 * 2;
static constexpr size_t OFF_H12 = OFF_W2 + SZ_W2;             // [2][128][1024] f16 : [b][0:512]=h1, [512:1024]=h2
static constexpr size_t SZ_H12  = (size_t)2 * 128 * 1024 * 2;
static constexpr size_t OFF_B1  = OFF_H12 + SZ_H12;           // [2048] f32 combined bias layer1
static constexpr size_t OFF_B2  = OFF_B1 + 2048 * 4;          // [2048] f32 combined bias layer2
static constexpr size_t OFF_FLG = OFF_B2 + 2048 * 4;          // 512 ints: flag1[8][32], flag2[8][32]

__global__ void setup_kernel(const float* __restrict__ w_ih1, const float* __restrict__ w_hh1,
                             const float* __restrict__ b_ih1, const float* __restrict__ b_hh1,
                             const float* __restrict__ w_ih2, const float* __restrict__ w_hh2,
                             const float* __restrict__ b_ih2, const float* __restrict__ b_hh2,
                             _Float16* __restrict__ W1f, _Float16* __restrict__ W2f,
                             _Float16* __restrict__ h12, float* __restrict__ bias1,
                             float* __restrict__ bias2, int* __restrict__ flags)
{
  const int idx = blockIdx.x * blockDim.x + threadIdx.x;
  const int str = gridDim.x * blockDim.x;
  for (int i = idx; i < 2048 * 576; i += str) {
    const int r = i / 576, k = i - r * 576;
    const float v = (k < 64) ? w_ih1[r * 64 + k] : w_hh1[r * 512 + (k - 64)];
    W1f[i] = (_Float16)v;
  }
  for (int i = idx; i < 2048 * 1024; i += str) {
    const int r = i >> 10, k = i & 1023;
    const float v = (k < 512) ? w_ih2[r * 512 + k] : w_hh2[r * 512 + (k - 512)];
    W2f[i] = (_Float16)v;
  }
  for (int i = idx; i < 2 * 128 * 1024; i += str) h12[i] = (_Float16)0.0f;
  for (int i = idx; i < 2048; i += str) {
    bias1[i] = b_ih1[i] + b_hh1[i];
    bias2[i] = b_ih2[i] + b_hh2[i];
  }
  for (int i = idx; i < 512; i += str) flags[i] = 0;
}

__device__ __forceinline__ float sigm(float v) { return 1.0f / (1.0f + __expf(-v)); }
__device__ __forceinline__ float tanh_fast(float v) {
  v = fminf(fmaxf(v, -15.0f), 15.0f);
  const float e = __expf(2.0f * v);
  return (e - 1.0f) / (e + 1.0f);
}

__device__ __forceinline__ u64 ld_a_u64(const u64* p) {
  return __hip_atomic_load(p, __ATOMIC_RELAXED, SCOPE_AGENT);
}
__device__ __forceinline__ void st_a_u64(u64* p, u64 v) {
  __hip_atomic_store(p, v, __ATOMIC_RELAXED, SCOPE_AGENT);
}

__device__ __forceinline__ half8 cvt_x(const floatx4 x0, const floatx4 x1) {
  half8 av;
  av[0] = (_Float16)x0[0]; av[1] = (_Float16)x0[1];
  av[2] = (_Float16)x0[2]; av[3] = (_Float16)x0[3];
  av[4] = (_Float16)x1[0]; av[5] = (_Float16)x1[1];
  av[6] = (_Float16)x1[2]; av[7] = (_Float16)x1[3];
  return av;
}

// Grid: 128 WGs x 512 thr, cooperative. WG = (gp = wg&3, jj = wg>>2). Owns units U0=jj*16 for TWO
// independent batch groups: A = gp (rows gp*16..), B = gp+4 (rows gp*16+64..). Superstep s advances
// both groups one timestep, ping-ponged so each group's MALL publish->detect round trip is hidden
// under the other group's compute:
//   bar / MFMA A / bar / [ewA+publishA (waves 0-3) || pollB+stageB (waves 4-7)] /
//   bar / MFMA B / bar / [ewB+publishB (waves 4-7) || pollA+stageA(s+1) (waves 0-3)]
// All intra-WG handoffs cross __syncthreads (4/superstep). Cross-WG: round-1-proven flag protocol
// (vmcnt-drained relaxed agent store, distributed per-wave poll). h-stage XOR-swizzled u64 (round-2
// proven). W2 h1-half in LDS (W2s), W1 + W2 h2-half rows in VGPRs.
// ROUND-5 FIX: staging loop trip counts. 256-thread staging loops need i<16 (256*16 = 4096 u64 =
// full h1+h2 stage); 512-thread prologue needs i<8. Round 4 used i<8/i<4 -> h2 half of hstg was
// NEVER written (half = idx>>11 always 0) -> uninitialized LDS -> NaN.
__global__ __launch_bounds__(512, 1)
void lstm_kernel(const float* __restrict__ x,
                 const _Float16* __restrict__ W1f,
                 const _Float16* __restrict__ W2f,
                 const float* __restrict__ bias1,
                 const float* __restrict__ bias2,
                 const float* __restrict__ w_out,
                 const float* __restrict__ b_out,
                 _Float16* __restrict__ h12,
                 int* __restrict__ flags,
                 float* __restrict__ out)
{
  __shared__ __align__(16) _Float16 W2s[64 * 520];    // h1-half of W2 rows (gate*16+u), K 0..511
  __shared__ __align__(16) u64 hstg[2][2][16][128];   // [grp A/B][0=h1(s-1),1=h2(s-2)]; 16B-chunk swizzled
  __shared__ float gbuf[2][2][4][16][20];             // [grp][layer][gate][unit][batch(+pad)]

  const int wg   = blockIdx.x;
  const int gp   = wg & 3;
  const int jj   = wg >> 2;
  const int U0   = jj * 16;
  const int B0A  = gp * 16;
  const int B0B  = gp * 16 + 64;
  const int tid  = threadIdx.x;
  const int lane = tid & 63;
  const int wv   = tid >> 6;
  const int lrow = lane & 15;
  const int quad = lane >> 4;

  int* f1A = flags + gp * 32;                // flag1[gp][jj]
  int* f2A = flags + 256 + gp * 32;
  int* f1B = flags + (gp + 4) * 32;
  int* f2B = flags + 256 + (gp + 4) * 32;
  u64* hb  = (u64*)h12;

  // ---- stage h1-half of W2 into LDS (once) ----
  for (int c = tid; c < 64 * 128; c += 512) {
    const int r  = c >> 7;
    const int cc = c & 127;
    const int grow = ((r >> 4) << 9) + U0 + (r & 15);
    *(u64*)&W2s[r * 520 + cc * 4] = *(const u64*)&W2f[(size_t)grow * 1024 + cc * 4];
  }

  // ---- recurrent weights -> VGPRs (rows per lane fixed) ----
  half8 wreg[18];                            // waves 0-3: W1 (18 kb); waves 4-7: W2 h2-half (16 kb)
  if (wv < 4) {
    const _Float16* wp = W1f + (size_t)((wv & 3) * 512 + U0 + lrow) * 576 + quad * 8;
#pragma unroll
    for (int kb = 0; kb < 18; ++kb) wreg[kb] = *(const half8*)(wp + kb * 32);
  } else {
    const _Float16* wp = W2f + (size_t)((wv & 3) * 512 + U0 + lrow) * 1024 + 512 + quad * 8;
#pragma unroll
    for (int kb = 0; kb < 16; ++kb) wreg[kb] = *(const half8*)(wp + kb * 32);
  }

  const _Float16* w2l = W2s + ((wv & 3) * 16 + lrow) * 520 + quad * 8;
  const float* xrwA = x + (size_t)(B0A + lrow) * (T_LEN * 64) + quad * 8;
  const float* xrwB = x + (size_t)(B0B + lrow) * (T_LEN * 64) + quad * 8;

  // ew state: wave0 = c1A, wave1 = c2A, wave4 = c1B, wave5 = c2B (4 cells/lane)
  float cst[4] = {0.f, 0.f, 0.f, 0.f};
  float bw[4][4];
  if (wv == 0 || wv == 4 || wv == 1 || wv == 5) {
    const float* bsrc = (wv == 0 || wv == 4) ? bias1 : bias2;
#pragma unroll
    for (int gg = 0; gg < 4; ++gg)
#pragma unroll
      for (int j = 0; j < 4; ++j) bw[gg][j] = bsrc[gg * 512 + U0 + (lane >> 4) * 4 + j];
  }
  float bo = 0.f;
  if (wv == 2 || wv == 3) bo = b_out[jj * 2 + (wv - 2)];
  if (wv == 6 || wv == 7) bo = b_out[jj * 2 + (wv - 6)];

  const int rx = (lrow & 7) << 4;            // byte XOR key for fragment reads
  const int qx = quad << 4;

  // ---- prologue: stage A for s=0 (h1A(-1) par 1, h2A(-2) par 0 — zeros); 512 thr x 8 = 4096 u64 ----
  {
    const u64* h1src = hb + 32768;
    const u64* h2src = hb;
#pragma unroll
    for (int i = 0; i < 8; ++i) {
      const int idx  = tid + i * 512;
      const int half = idx >> 11;
      const int r    = (idx >> 7) & 15;
      const int cc   = idx & 127;
      const u64 v = half ? ld_a_u64(h2src + (size_t)(B0A + r) * 256 + 128 + cc)
                         : ld_a_u64(h1src + (size_t)(B0A + r) * 256 + cc);
      hstg[0][half][r][cc ^ ((r & 7) << 1)] = v;
    }
  }

  // ---- x prefetch for s=0 ----
  floatx4 xa0, xa1, xa2, xa3, xb0, xb1, xb2, xb3;
  if (wv < 4) {
    xa0 = *(const floatx4*)(xrwA + 0);  xa1 = *(const floatx4*)(xrwA + 4);
    xa2 = *(const floatx4*)(xrwA + 32); xa3 = *(const floatx4*)(xrwA + 36);
    xb0 = *(const floatx4*)(xrwB + 0);  xb1 = *(const floatx4*)(xrwB + 4);
    xb2 = *(const floatx4*)(xrwB + 32); xb3 = *(const floatx4*)(xrwB + 36);
  }

#pragma unroll 1
  for (int s = 0; s < NSTEP; ++s) {
    const int pc = s & 1;                    // parity of h1(s) / h2(s-2)
    const int pp = (s - 1) & 1;              // parity of h1(s-1) / h2(s-1)

    __syncthreads();                         // (2): hstg[A] staged for s; gbuf free

    // ================= MFMA A =================
    if (wv < 4) {
      if (s < T_LEN) {
        floatx4 a0 = {0.f, 0.f, 0.f, 0.f};
        floatx4 a1 = {0.f, 0.f, 0.f, 0.f};
        a0 = MFMA16(cvt_x(xa0, xa1), wreg[0], a0);
        a1 = MFMA16(cvt_x(xa2, xa3), wreg[1], a1);
        const char* rb = (const char*)&hstg[0][0][lrow][0];
#pragma unroll
        for (int kb = 2; kb < 18; ++kb) {
          const half8 av = *(const half8*)(rb + ((((kb - 2) << 6) | qx) ^ rx));
          if (kb & 1) a1 = MFMA16(av, wreg[kb], a1);
          else        a0 = MFMA16(av, wreg[kb], a0);
        }
        const floatx4 a = a0 + a1;
        *(floatx4*)(&gbuf[0][0][wv][lrow][quad * 4]) = a;
      }
      if (s + 1 < T_LEN) {                   // prefetch x-A for s+1 (lands during slots 4-9)
        const float* xr = xrwA + (size_t)(s + 1) * 64;
        xa0 = *(const floatx4*)(xr + 0);  xa1 = *(const floatx4*)(xr + 4);
        xa2 = *(const floatx4*)(xr + 32); xa3 = *(const floatx4*)(xr + 36);
      }
    } else {
      if (s >= 1 && s <= T_LEN) {
        floatx4 a0 = {0.f, 0.f, 0.f, 0.f};
        floatx4 a1 = {0.f, 0.f, 0.f, 0.f};
        const char* rb0 = (const char*)&hstg[0][0][lrow][0];
        const char* rb1 = (const char*)&hstg[0][1][lrow][0];
#pragma unroll
        for (int kb = 0; kb < 16; ++kb) {    // h1A(s-1) x W2s(LDS)
          const half8 av = *(const half8*)(rb0 + (((kb << 6) | qx) ^ rx));
          const half8 bv = *(const half8*)(w2l + kb * 32);
          if (kb & 1) a1 = MFMA16(av, bv, a1);
          else        a0 = MFMA16(av, bv, a0);
        }
#pragma unroll
        for (int kb = 0; kb < 16; ++kb) {    // h2A(s-2) x W2 h2-half (VGPR)
          const half8 av = *(const half8*)(rb1 + (((kb << 6) | qx) ^ rx));
          if (kb & 1) a1 = MFMA16(av, wreg[kb], a1);
          else        a0 = MFMA16(av, wreg[kb], a0);
        }
        const floatx4 a = a0 + a1;
        *(floatx4*)(&gbuf[0][1][wv & 3][lrow][quad * 4]) = a;
      }
    }

    __syncthreads();                         // (4): gbuf[A] ready

    // ========= slot 5: ew A (waves 0-3) || poll+stage B (waves 4-7) =========
    if (wv == 0) {
      if (s < T_LEN) {                       // h1A(s)
        const int eb = lane & 15, qq = lane >> 4;
        union { half4 h; u64 u; } pk;
#pragma unroll
        for (int j = 0; j < 4; ++j) {
          const int eu = qq * 4 + j;
          const float s0 = gbuf[0][0][0][eu][eb] + bw[0][j];
          const float s1 = gbuf[0][0][1][eu][eb] + bw[1][j];
          const float s2 = gbuf[0][0][2][eu][eb] + bw[2][j];
          const float s3 = gbuf[0][0][3][eu][eb] + bw[3][j];
          const float iv = sigm(s0), fv = sigm(s1);
          const float gv = tanh_fast(s2), ov = sigm(s3);
          cst[j] = fv * cst[j] + iv * gv;
          pk.h[j] = (_Float16)(ov * tanh_fast(cst[j]));
        }
        st_a_u64(hb + (size_t)pc * 32768 + (size_t)(B0A + eb) * 256 + (U0 >> 2) + qq, pk.u);
      }
      asm volatile("s_waitcnt vmcnt(0)" ::: "memory");
      if (lane == 0)
        __hip_atomic_store(&f1A[jj], s + 1, __ATOMIC_RELAXED, SCOPE_AGENT);
    } else if (wv == 1) {
      if (s >= 1 && s <= T_LEN) {            // h2A(s-1)
        const int eb = lane & 15, qq = lane >> 4;
        union { half4 h; u64 u; } pk;
#pragma unroll
        for (int j = 0; j < 4; ++j) {
          const int eu = qq * 4 + j;
          const float s0 = gbuf[0][1][0][eu][eb] + bw[0][j];
          const float s1 = gbuf[0][1][1][eu][eb] + bw[1][j];
          const float s2 = gbuf[0][1][2][eu][eb] + bw[2][j];
          const float s3 = gbuf[0][1][3][eu][eb] + bw[3][j];
          const float iv = sigm(s0), fv = sigm(s1);
          const float gv = tanh_fast(s2), ov = sigm(s3);
          cst[j] = fv * cst[j] + iv * gv;
          pk.h[j] = (_Float16)(ov * tanh_fast(cst[j]));
        }
        st_a_u64(hb + (size_t)pp * 32768 + (size_t)(B0A + eb) * 256 + 128 + (U0 >> 2) + qq, pk.u);
        asm volatile("s_waitcnt vmcnt(0)" ::: "memory");
        if (lane == 0)
          __hip_atomic_store(&f2A[jj], s, __ATOMIC_RELAXED, SCOPE_AGENT);
      }
    } else if (wv < 4) {
      if (s >= 2) {                          // yA(s-2) from hstg[0][1]
        const int b  = lane >> 2;
        const int kp = lane & 3;
        const int oi = jj * 2 + (wv - 2);
        const char* rbY = (const char*)&hstg[0][1][b][0];
        const int bx = (b & 7) << 4;
        const float* wrb = w_out + oi * 512 + kp * 128;
        float sacc = 0.f;
#pragma unroll
        for (int kc0 = 0; kc0 < 16; ++kc0) {
          const int kc = (kc0 + 2 * kp) & 15;
          const half8  hv8 = *(const half8*)(rbY + (((kp * 16 + kc) << 4) ^ bx));
          const floatx4 w0 = *(const floatx4*)(wrb + kc * 8);
          const floatx4 w1 = *(const floatx4*)(wrb + kc * 8 + 4);
          sacc += (float)hv8[0] * w0[0] + (float)hv8[1] * w0[1]
                + (float)hv8[2] * w0[2] + (float)hv8[3] * w0[3]
                + (float)hv8[4] * w1[0] + (float)hv8[5] * w1[1]
                + (float)hv8[6] * w1[2] + (float)hv8[7] * w1[3];
        }
        sacc += __shfl_xor(sacc, 1);
        sacc += __shfl_xor(sacc, 2);
        if (kp == 0)
          out[((size_t)(B0A + b) * T_LEN + (s - 2)) * 64 + oi] = sacc + bo;
      }
    } else {
      // poll B: h1B(s-1) needs flag1B >= s ; h2B(s-2) needs flag2B >= s-1
      {
        int* fp = (lane < 32) ? (f1B + lane) : (f2B + (lane - 32));
        const int thr = (lane < 32) ? s : (s - 1);
        while (!__all(__hip_atomic_load(fp, __ATOMIC_RELAXED, SCOPE_AGENT) >= thr))
          __builtin_amdgcn_s_sleep(1);
        asm volatile("" ::: "memory");
      }
      // stage B: h1B(s-1) @ parity pp ; h2B(s-2) @ parity pc ; 256 thr x 16 = 4096 u64
      const u64* h1src = hb + (size_t)pp * 32768;
      const u64* h2src = hb + (size_t)pc * 32768;
      const int ctid = tid - 256;
#pragma unroll
      for (int i = 0; i < 16; ++i) {
        const int idx  = ctid + i * 256;
        const int half = idx >> 11;
        const int r    = (idx >> 7) & 15;
        const int cc   = idx & 127;
        const u64 v = half ? ld_a_u64(h2src + (size_t)(B0B + r) * 256 + 128 + cc)
                           : ld_a_u64(h1src + (size_t)(B0B + r) * 256 + cc);
        hstg[1][half][r][cc ^ ((r & 7) << 1)] = v;
      }
    }

    __syncthreads();                         // (6): hstg[B] staged; ew A done

    // ================= MFMA B =================
    if (wv < 4) {
      if (s < T_LEN) {
        floatx4 a0 = {0.f, 0.f, 0.f, 0.f};
        floatx4 a1 = {0.f, 0.f, 0.f, 0.f};
        a0 = MFMA16(cvt_x(xb0, xb1), wreg[0], a0);
        a1 = MFMA16(cvt_x(xb2, xb3), wreg[1], a1);
        const char* rb = (const char*)&hstg[1][0][lrow][0];
#pragma unroll
        for (int kb = 2; kb < 18; ++kb) {
          const half8 av = *(const half8*)(rb + ((((kb - 2) << 6) | qx) ^ rx));
          if (kb & 1) a1 = MFMA16(av, wreg[kb], a1);
          else        a0 = MFMA16(av, wreg[kb], a0);
        }
        const floatx4 a = a0 + a1;
        *(floatx4*)(&gbuf[1][0][wv][lrow][quad * 4]) = a;
      }
      if (s + 1 < T_LEN) {                   // prefetch x-B for s+1
        const float* xr = xrwB + (size_t)(s + 1) * 64;
        xb0 = *(const floatx4*)(xr + 0);  xb1 = *(const floatx4*)(xr + 4);
        xb2 = *(const floatx4*)(xr + 32); xb3 = *(const floatx4*)(xr + 36);
      }
    } else {
      if (s >= 1 && s <= T_LEN) {
        floatx4 a0 = {0.f, 0.f, 0.f, 0.f};
        floatx4 a1 = {0.f, 0.f, 0.f, 0.f};
        const char* rb0 = (const char*)&hstg[1][0][lrow][0];
        const char* rb1 = (const char*)&hstg[1][1][lrow][0];
#pragma unroll
        for (int kb = 0; kb < 16; ++kb) {
          const half8 av = *(const half8*)(rb0 + (((kb << 6) | qx) ^ rx));
          const half8 bv = *(const half8*)(w2l + kb * 32);
          if (kb & 1) a1 = MFMA16(av, bv, a1);
          else        a0 = MFMA16(av, bv, a0);
        }
#pragma unroll
        for (int kb = 0; kb < 16; ++kb) {
          const half8 av = *(const half8*)(rb1 + (((kb << 6) | qx) ^ rx));
          if (kb & 1) a1 = MFMA16(av, wreg[kb], a1);
          else        a0 = MFMA16(av, wreg[kb], a0);
        }
        const floatx4 a = a0 + a1;
        *(floatx4*)(&gbuf[1][1][wv & 3][lrow][quad * 4]) = a;
      }
    }

    __syncthreads();                         // (8): gbuf[B] ready

    // ========= slot 9: ew B (waves 4-7) || poll+stage A(s+1) (waves 0-3) =========
    if (wv == 4) {
      if (s < T_LEN) {                       // h1B(s)
        const int eb = lane & 15, qq = lane >> 4;
        union { half4 h; u64 u; } pk;
#pragma unroll
        for (int j = 0; j < 4; ++j) {
          const int eu = qq * 4 + j;
          const float s0 = gbuf[1][0][0][eu][eb] + bw[0][j];
          const float s1 = gbuf[1][0][1][eu][eb] + bw[1][j];
          const float s2 = gbuf[1][0][2][eu][eb] + bw[2][j];
          const float s3 = gbuf[1][0][3][eu][eb] + bw[3][j];
          const float iv = sigm(s0), fv = sigm(s1);
          const float gv = tanh_fast(s2), ov = sigm(s3);
          cst[j] = fv * cst[j] + iv * gv;
          pk.h[j] = (_Float16)(ov * tanh_fast(cst[j]));
        }
        st_a_u64(hb + (size_t)pc * 32768 + (size_t)(B0B + eb) * 256 + (U0 >> 2) + qq, pk.u);
      }
      asm volatile("s_waitcnt vmcnt(0)" ::: "memory");
      if (lane == 0)
        __hip_atomic_store(&f1B[jj], s + 1, __ATOMIC_RELAXED, SCOPE_AGENT);
    } else if (wv == 5) {
      if (s >= 1 && s <= T_LEN) {            // h2B(s-1)
        const int eb = lane & 15, qq = lane >> 4;
        union { half4 h; u64 u; } pk;
#pragma unroll
        for (int j = 0; j < 4; ++j) {
          const int eu = qq * 4 + j;
          const float s0 = gbuf[1][1][0][eu][eb] + bw[0][j];
          const float s1 = gbuf[1][1][1][eu][eb] + bw[1][j];
          const float s2 = gbuf[1][1][2][eu][eb] + bw[2][j];
          const float s3 = gbuf[1][1][3][eu][eb] + bw[3][j];
          const float iv = sigm(s0), fv = sigm(s1);
          const float gv = tanh_fast(s2), ov = sigm(s3);
          cst[j] = fv * cst[j] + iv * gv;
          pk.h[j] = (_Float16)(ov * tanh_fast(cst[j]));
        }
        st_a_u64(hb + (size_t)pp * 32768 + (size_t)(B0B + eb) * 256 + 128 + (U0 >> 2) + qq, pk.u);
        asm volatile("s_waitcnt vmcnt(0)" ::: "memory");
        if (lane == 0)
          __hip_atomic_store(&f2B[jj], s, __ATOMIC_RELAXED, SCOPE_AGENT);
      }
    } else if (wv >= 6) {
      if (s >= 2) {                          // yB(s-2) from hstg[1][1]
        const int b  = lane >> 2;
        const int kp = lane & 3;
        const int oi = jj * 2 + (wv - 6);
        const char* rbY = (const char*)&hstg[1][1][b][0];
        const int bx = (b & 7) << 4;
        const float* wrb = w_out + oi * 512 + kp * 128;
        float sacc = 0.f;
#pragma unroll
        for (int kc0 = 0; kc0 < 16; ++kc0) {
          const int kc = (kc0 + 2 * kp) & 15;
          const half8  hv8 = *(const half8*)(rbY + (((kp * 16 + kc) << 4) ^ bx));
          const floatx4 w0 = *(const floatx4*)(wrb + kc * 8);
          const floatx4 w1 = *(const floatx4*)(wrb + kc * 8 + 4);
          sacc += (float)hv8[0] * w0[0] + (float)hv8[1] * w0[1]
                + (float)hv8[2] * w0[2] + (float)hv8[3] * w0[3]
                + (float)hv8[4] * w1[0] + (float)hv8[5] * w1[1]
                + (float)hv8[6] * w1[2] + (float)hv8[7] * w1[3];
        }
        sacc += __shfl_xor(sacc, 1);
        sacc += __shfl_xor(sacc, 2);
        if (kp == 0)
          out[((size_t)(B0B + b) * T_LEN + (s - 2)) * 64 + oi] = sacc + bo;
      }
    } else {
      if (s + 1 < NSTEP) {
        // poll A(s+1): h1A(s) needs flag1A >= s+1 ; h2A(s-1) needs flag2A >= s
        {
          int* fp = (lane < 32) ? (f1A + lane) : (f2A + (lane - 32));
          const int thr = (lane < 32) ? (s + 1) : s;
          while (!__all(__hip_atomic_load(fp, __ATOMIC_RELAXED, SCOPE_AGENT) >= thr))
            __builtin_amdgcn_s_sleep(1);
          asm volatile("" ::: "memory");
        }
        // stage A(s+1): h1A(s) @ parity pc ; h2A(s-1) @ parity pp ; 256 thr x 16 = 4096 u64
        const u64* h1src = hb + (size_t)pc * 32768;
        const u64* h2src = hb + (size_t)pp * 32768;
#pragma unroll
        for (int i = 0; i < 16; ++i) {
          const int idx  = tid + i * 256;
          const int half = idx >> 11;
          const int r    = (idx >> 7) & 15;
          const int cc   = idx & 127;
          const u64 v = half ? ld_a_u64(h2src + (size_t)(B0A + r) * 256 + 128 + cc)
                             : ld_a_u64(h1src + (size_t)(B0A + r) * 256 + cc);
          hstg[0][half][r][cc ^ ((r & 7) << 1)] = v;
        }
      }
    }
  }
}

extern "C" void kernel_launch(void* const* d_in, const int* in_sizes, int n_in,
                              void* d_out, int out_size, void* d_ws, size_t ws_size,
                              hipStream_t stream) {
  (void)in_sizes; (void)n_in; (void)out_size; (void)ws_size;

  const float* x      = (const float*)d_in[0];
  const float* w_ih1  = (const float*)d_in[1];
  const float* w_hh1  = (const float*)d_in[2];
  const float* b_ih1  = (const float*)d_in[3];
  const float* b_hh1  = (const float*)d_in[4];
  const float* w_ih2  = (const float*)d_in[5];
  const float* w_hh2  = (const float*)d_in[6];
  const float* b_ih2  = (const float*)d_in[7];
  const float* b_hh2  = (const float*)d_in[8];
  const float* w_out  = (const float*)d_in[9];
  const float* b_out  = (const float*)d_in[10];

  char* ws = (char*)d_ws;
  _Float16* W1f   = (_Float16*)(ws + OFF_W1);
  _Float16* W2f   = (_Float16*)(ws + OFF_W2);
  _Float16* h12   = (_Float16*)(ws + OFF_H12);
  float*    bias1 = (float*)(ws + OFF_B1);
  float*    bias2 = (float*)(ws + OFF_B2);
  int*      flags = (int*)(ws + OFF_FLG);
  float*    outp  = (float*)d_out;

  hipLaunchKernelGGL(setup_kernel, dim3(1024), dim3(256), 0, stream,
                     w_ih1, w_hh1, b_ih1, b_hh1, w_ih2, w_hh2, b_ih2, b_hh2,
                     W1f, W2f, h12, bias1, bias2, flags);

  void* args[] = { (void*)&x, (void*)&W1f, (void*)&W2f, (void*)&bias1, (void*)&bias2,
                   (void*)&w_out, (void*)&b_out, (void*)&h12, (void*)&flags, (void*)&outp };
  hipLaunchCooperativeKernel((void*)lstm_kernel, dim3(128), dim3(512), args, 0, stream);
}